// Round 2
// baseline (15.954 us; speedup 1.0000x reference)
//
#include <hip/hip_runtime.h>
#include <math.h>

#define NGRID 100

// One thread per point. Each point splats amp * g_range(j) * g_dop(i) into
// out[b, i, j] for the tiny set of bins where the Gaussians are
// non-negligible (10-sigma cutoff; truncation <= 8000*exp(-50) ~ 1e-18).
//
// The harness's ground truth is a float64 numpy recomputation (ref=np).
// The doppler sigma is ~9.66e-5 while dop comes from O(1) intermediates
// scaled by ~64.7, so fp32 rounding in the kinematics chain is a ~0.5-sigma
// shift -> ~2% image error (round-1 failure at 2.34e-2). Therefore the whole
// per-point chain runs in double; only the final accumulate is fp32.
__global__ __launch_bounds__(256) void isar_splat(
        const float* __restrict__ pts,
        const float* __restrict__ nrm,
        const float* __restrict__ los,
        const float* __restrict__ spin,
        const float* __restrict__ omega,
        float* __restrict__ out,
        int BN, int N) {
    int idx = blockIdx.x * blockDim.x + threadIdx.x;
    if (idx >= BN) return;

    const double L0 = (double)los[0], L1 = (double)los[1], L2 = (double)los[2];
    const double S0 = (double)spin[0], S1 = (double)spin[1], S2 = (double)spin[2];
    const double Om = (double)omega[0];

    const float* pp = pts + (size_t)idx * 3;
    const float* nn = nrm + (size_t)idx * 3;
    const double p0 = (double)pp[0], p1 = (double)pp[1], p2 = (double)pp[2];
    const double n0 = (double)nn[0], n1 = (double)nn[1], n2 = (double)nn[2];

    // amp = clip(-4.0 * dot(L, n), 0, 1)
    double amp = -4.0 * (L0 * n0 + L1 * n1 + L2 * n2);
    if (!(amp > 0.0)) return;          // zero contribution
    amp = fmin(amp, 1.0);

    // v = cross(S, p); vrad = Omega * dot(L, v)
    double v0 = S1 * p2 - S2 * p1;
    double v1 = S2 * p0 - S0 * p2;
    double v2 = S0 * p1 - S1 * p0;
    double vrad = Om * (L0 * v0 + L1 * v1 + L2 * v2);

    const double LAM = 299792458.0 / 9.7e9;              // LAMBDA1
    double dop = -2.0 * vrad / LAM;
    double rng = L0 * p0 + L1 * p1 + L2 * p2;

    double dsig = LAM / 2.0 / Om / 160.0;                // doppler_res
    const double rsig = 299792458.0 / 4.8e9 / 2.0 * 5.0; // RANGE_RES

    const double CUT = 10.0;

    // doppler bins at -3 + i*(6/99), i in [0,100)
    double ddlo = (dop - CUT * dsig + 3.0) * (99.0 / 6.0);
    double ddhi = (dop + CUT * dsig + 3.0) * (99.0 / 6.0);
    if (ddhi < -1.0 || ddlo > (double)(NGRID + 1)) return;
    int i0 = max(0, (int)floor(ddlo) - 1);
    int i1 = min(NGRID - 1, (int)ceil(ddhi) + 1);
    if (i0 > i1) return;

    // range bins at -10 + j*(20/99), j in [0,100)
    double rrlo = (rng - CUT * rsig + 10.0) * (99.0 / 20.0);
    double rrhi = (rng + CUT * rsig + 10.0) * (99.0 / 20.0);
    if (rrhi < -1.0 || rrlo > (double)(NGRID + 1)) return;
    int j0 = max(0, (int)floor(rrlo) - 1);
    int j1 = min(NGRID - 1, (int)ceil(rrhi) + 1);
    if (j0 > j1) return;

    int b = idx / N;
    float* outb = out + (size_t)b * NGRID * NGRID;

    for (int i = i0; i <= i1; ++i) {
        double dbin = -3.0 + (double)i * (6.0 / 99.0);
        double qd = (dop - dbin) / dsig;
        double gd = exp(-0.5 * qd * qd);
        if (gd == 0.0) continue;
        for (int j = j0; j <= j1; ++j) {
            double rbin = -10.0 + (double)j * (20.0 / 99.0);
            double qr = (rng - rbin) / rsig;
            double gr = exp(-0.5 * qr * qr);
            double c = amp * gr * gd;
            float cf = (float)c;
            if (cf != 0.0f)
                atomicAdd(&outb[i * NGRID + j], cf);
        }
    }
}

extern "C" void kernel_launch(void* const* d_in, const int* in_sizes, int n_in,
                              void* d_out, int out_size, void* d_ws, size_t ws_size,
                              hipStream_t stream) {
    const float* pts  = (const float*)d_in[0];   // [B,N,3]
    const float* nrm  = (const float*)d_in[1];   // [B,N,3]
    const float* los  = (const float*)d_in[2];   // [1,3]
    const float* spin = (const float*)d_in[3];   // [1,3]
    const float* om   = (const float*)d_in[4];   // [1,1]
    float* out = (float*)d_out;                  // [B,100,100]

    int BN = in_sizes[0] / 3;
    int B  = out_size / (NGRID * NGRID);
    if (B < 1) B = 1;
    int N  = BN / B;

    hipMemsetAsync(d_out, 0, (size_t)out_size * sizeof(float), stream);

    int threads = 256;
    int blocks = (BN + threads - 1) / threads;
    isar_splat<<<blocks, threads, 0, stream>>>(pts, nrm, los, spin, om, out, BN, N);
}